// Round 1
// baseline (1354.605 us; speedup 1.0000x reference)
//
#include <hip/hip_runtime.h>
#include <math.h>

#define BB 32
#define MM 2048
#define NN 512
#define PSZ 16
#define HH 640
#define WW 640
#define DD 256
#define DIMG_ 384
#define NHEADS 8
#define PD_ 768
#define TWO_N 1024

#define PE_ELEMS (BB * TWO_N * DD)          // 8,388,608 floats
#define U_ELEMS  (BB * NHEADS * DD)         // 65,536 floats

// ---------------------------------------------------------------------------
// Kernel 1: q = embs @ W_proj.T + b_proj ; q2 = q @ Wq.T + bq ;
//           u[b,h,:] = Wk_h^T q2_h ; ubias[b,h] = q2_h . bk_h
// ---------------------------------------------------------------------------
__global__ __launch_bounds__(256) void qproj_kernel(
    const float* __restrict__ image_embs,
    const float* __restrict__ W_proj, const float* __restrict__ b_proj,
    const float* __restrict__ in_w,   const float* __restrict__ in_b,
    float* __restrict__ u_out, float* __restrict__ bias_out)
{
  __shared__ float q1[DD];
  __shared__ float q2[DD];
  const int t = threadIdx.x;
  const int b = blockIdx.x;

  // q1 = image_embs @ W_proj.T + b_proj
  {
    const float* emb = image_embs + (size_t)b * DIMG_;
    const float* wr  = W_proj + (size_t)t * DIMG_;
    float a = b_proj[t];
    for (int i = 0; i < DIMG_; ++i) a += emb[i] * wr[i];
    q1[t] = a;
  }
  __syncthreads();
  // q2 = q1 @ Wq.T + bq   (Wq = in_w[0:256])
  {
    const float* wr = in_w + (size_t)t * DD;
    float a = in_b[t];
    for (int i = 0; i < DD; ++i) a += q1[i] * wr[i];
    q2[t] = a;
  }
  __syncthreads();
  // u[h][t] = sum_i q2[h*32+i] * Wk[h*32+i][t]  (Wk rows = in_w[256..511])
  #pragma unroll
  for (int h = 0; h < NHEADS; ++h) {
    float s = 0.0f;
    #pragma unroll 8
    for (int i = 0; i < 32; ++i)
      s += q2[h * 32 + i] * in_w[(size_t)(DD + h * 32 + i) * DD + t];
    u_out[((size_t)b * NHEADS + h) * DD + t] = s;
  }
  if (t < NHEADS) {
    float s = 0.0f;
    for (int i = 0; i < 32; ++i) s += q2[t * 32 + i] * in_b[DD + t * 32 + i];
    bias_out[b * NHEADS + t] = s;
  }
}

// ---------------------------------------------------------------------------
// Kernel 2: patch extraction + LN1 + (x @ W_pe.T + b_pe) + LN2 + score append
// 16 patches per block, 256 threads. Writes pe[32768][256] fp32 to ws.
// ---------------------------------------------------------------------------
__global__ __launch_bounds__(256) void patch_pe_kernel(
    const float* __restrict__ im0, const float* __restrict__ im1,
    const float* __restrict__ kpts0, const float* __restrict__ kpts1,
    const float* __restrict__ scores0, const float* __restrict__ scores1,
    const int*   __restrict__ sorted_matches,
    const float* __restrict__ ln1_g, const float* __restrict__ ln1_b,
    const float* __restrict__ W_pe,  const float* __restrict__ b_pe,
    const float* __restrict__ ln2_g, const float* __restrict__ ln2_b,
    float* __restrict__ pe_out)
{
  __shared__ __align__(16) float A[16][PD_];   // 49152 B
  __shared__ int   sx0[16], sy0[16], svalid[16];
  __shared__ float sscore[16], smu[16], srs[16];

  const int t   = threadIdx.x;
  const int blk = blockIdx.x;
  const int b      = blk >> 6;            // 64 blocks per batch (1024/16)
  const int n2base = (blk & 63) << 4;     // all 16 patches same side
  const bool side1 = (n2base >= NN);
  const float* img  = side1 ? im1 : im0;
  const float* kpts = side1 ? kpts1 : kpts0;
  const float* scrs = side1 ? scores1 : scores0;

  if (t < 16) {
    const int n2 = n2base + t;
    const int n  = side1 ? (n2 - NN) : n2;
    const int m0 = sorted_matches[((size_t)b * NN + n) * 2 + 0];
    const int m1 = sorted_matches[((size_t)b * NN + n) * 2 + 1];
    const int valid = (m1 > -1) ? 1 : 0;
    int midx = side1 ? m1 : m0;
    midx = min(max(midx, 0), MM - 1);
    const float kx = kpts[((size_t)b * MM + midx) * 2 + 0];
    const float ky = kpts[((size_t)b * MM + midx) * 2 + 1];
    const int cx = (int)rintf(kx);        // round-half-even == jnp.round
    const int cy = (int)rintf(ky);
    sx0[t] = min(max(cx - 8, 0), WW - PSZ);
    sy0[t] = min(max(cy - 8, 0), HH - PSZ);
    svalid[t] = valid;
    sscore[t] = valid ? scrs[(size_t)b * MM + midx] : 0.0f;
  }
  __syncthreads();

  // -------- extraction: 16*768 = 12288 pixels, 48 per thread --------
  const size_t imb = (size_t)b * 3 * HH * WW;
  #pragma unroll 4
  for (int i = 0; i < 48; ++i) {
    const int idx = i * 256 + t;
    const int p   = idx / PD_;
    const int rem = idx - p * PD_;
    const int c   = rem >> 8;
    const int r2  = rem & 255;
    const int py  = r2 >> 4;
    const int px  = r2 & 15;
    float v = -1.0f;
    if (svalid[p]) {
      const float pix = img[imb + ((size_t)c * HH + (sy0[p] + py)) * WW + sx0[p] + px];
      v = fminf(fmaxf(pix, 0.0f), 1.0f);
    }
    A[p][rem] = v;
  }
  __syncthreads();

  // -------- LN1 stats: 16 threads per patch --------
  {
    const int p = t >> 4, j = t & 15;
    float s = 0.0f, ss = 0.0f;
    #pragma unroll 8
    for (int i = 0; i < 48; ++i) { const float v = A[p][j + 16 * i]; s += v; ss += v * v; }
    #pragma unroll
    for (int m = 8; m; m >>= 1) { s += __shfl_xor(s, m, 16); ss += __shfl_xor(ss, m, 16); }
    if (j == 0) {
      const float mu  = s * (1.0f / 768.0f);
      const float var = ss * (1.0f / 768.0f) - mu * mu;
      smu[p] = mu;
      srs[p] = 1.0f / sqrtf(var + 1e-5f);
    }
  }
  __syncthreads();

  // -------- normalize in place (apply ln1_g / ln1_b) --------
  #pragma unroll 4
  for (int i = 0; i < 48; ++i) {
    const int idx = i * 256 + t;
    const int p   = idx / PD_;
    const int rem = idx - p * PD_;
    A[p][rem] = (A[p][rem] - smu[p]) * srs[p] * ln1_g[rem] + ln1_b[rem];
  }
  __syncthreads();

  // -------- GEMM: e[16][255] = A[16][768] @ W_pe.T --------
  // thread tile: 4 patches (by wave tp) x 4 cols (td, td+64, td+128, td+192)
  const int td = t & 63, tp = t >> 6;
  float acc[4][4];
  #pragma unroll
  for (int pp = 0; pp < 4; ++pp)
    #pragma unroll
    for (int cc = 0; cc < 4; ++cc) acc[pp][cc] = 0.0f;

  const float4* Arow0 = (const float4*)A[tp * 4 + 0];
  const float4* Arow1 = (const float4*)A[tp * 4 + 1];
  const float4* Arow2 = (const float4*)A[tp * 4 + 2];
  const float4* Arow3 = (const float4*)A[tp * 4 + 3];
  const float4* Wrow[4];
  #pragma unroll
  for (int cc = 0; cc < 4; ++cc) {
    const int c  = td + 64 * cc;
    const int cr = min(c, 254);           // c==255 is a dummy lane-col
    Wrow[cc] = (const float4*)(W_pe + (size_t)cr * PD_);
  }

  #pragma unroll 2
  for (int k4 = 0; k4 < PD_ / 4; ++k4) {
    const float4 a0 = Arow0[k4];          // wave-uniform -> LDS broadcast
    const float4 a1 = Arow1[k4];
    const float4 a2 = Arow2[k4];
    const float4 a3 = Arow3[k4];
    #pragma unroll
    for (int cc = 0; cc < 4; ++cc) {
      const float4 w = Wrow[cc][k4];
      acc[0][cc] += a0.x * w.x + a0.y * w.y + a0.z * w.z + a0.w * w.w;
      acc[1][cc] += a1.x * w.x + a1.y * w.y + a1.z * w.z + a1.w * w.w;
      acc[2][cc] += a2.x * w.x + a2.y * w.y + a2.z * w.z + a2.w * w.w;
      acc[3][cc] += a3.x * w.x + a3.y * w.y + a3.z * w.z + a3.w * w.w;
    }
  }

  // -------- + b_pe, LN2 over 255 cols (wave-wide reduce), store pe --------
  float e[4][4];
  #pragma unroll
  for (int pp = 0; pp < 4; ++pp)
    #pragma unroll
    for (int cc = 0; cc < 4; ++cc) {
      const int c = td + 64 * cc;
      e[pp][cc] = acc[pp][cc] + ((c < 255) ? b_pe[c] : 0.0f);
    }

  #pragma unroll
  for (int pp = 0; pp < 4; ++pp) {
    float s = 0.0f, ss = 0.0f;
    #pragma unroll
    for (int cc = 0; cc < 4; ++cc) {
      const int c = td + 64 * cc;
      if (c < 255) { s += e[pp][cc]; ss += e[pp][cc] * e[pp][cc]; }
    }
    #pragma unroll
    for (int m = 32; m; m >>= 1) { s += __shfl_xor(s, m, 64); ss += __shfl_xor(ss, m, 64); }
    const float mu  = s * (1.0f / 255.0f);
    const float var = ss * (1.0f / 255.0f) - mu * mu;
    const float rs  = 1.0f / sqrtf(var + 1e-5f);
    const int gp = blk * 16 + tp * 4 + pp;           // global patch index
    float* dst = pe_out + (size_t)gp * DD;
    #pragma unroll
    for (int cc = 0; cc < 4; ++cc) {
      const int c = td + 64 * cc;
      if (c < 255) dst[c] = (e[pp][cc] - mu) * rs * ln2_g[c] + ln2_b[c];
    }
    if (td == 0) dst[255] = sscore[tp * 4 + pp];
  }
}

// ---------------------------------------------------------------------------
// Kernel 3: per-batch attention (1 query, 1024 keys, 8 heads) + output head
// ---------------------------------------------------------------------------
__global__ __launch_bounds__(256) void attn_kernel(
    const float* __restrict__ pe, const float* __restrict__ u,
    const float* __restrict__ ubias,
    const float* __restrict__ in_w,  const float* __restrict__ in_b,
    const float* __restrict__ out_w, const float* __restrict__ out_b,
    const float* __restrict__ W_fc,  const float* __restrict__ b_fc,
    float* __restrict__ outp)
{
  __shared__ __align__(16) float lt[TWO_N * NHEADS];   // [key][h], 32 KB
  __shared__ float ctx_sh[NHEADS * DD];                // 8 KB
  __shared__ float o_sh[DD], o2_sh[DD];

  const int t = threadIdx.x;
  const int b = blockIdx.x;
  const float* peb = pe + (size_t)b * TWO_N * DD;
  const float* ub  = u + (size_t)b * NHEADS * DD;      // wave-uniform reads
  const float sc = 0.17677669529663687f;               // 1/sqrt(32)

  // -------- pass 1: logits for all keys, all heads --------
  for (int kk = 0; kk < 4; ++kk) {
    const int key = kk * 256 + t;
    const float4* row = (const float4*)(peb + (size_t)key * DD);
    float d[NHEADS] = {0, 0, 0, 0, 0, 0, 0, 0};
    for (int j4 = 0; j4 < DD / 4; ++j4) {
      const float4 v = row[j4];
      #pragma unroll
      for (int h = 0; h < NHEADS; ++h) {
        const float4 uu = *(const float4*)(ub + h * DD + j4 * 4);  // uniform
        d[h] += v.x * uu.x + v.y * uu.y + v.z * uu.z + v.w * uu.w;
      }
    }
    #pragma unroll
    for (int h = 0; h < NHEADS; ++h)
      lt[key * NHEADS + h] = (d[h] + ubias[b * NHEADS + h]) * sc;
  }
  __syncthreads();

  // -------- softmax per head: 32 threads per head --------
  {
    const int h = t >> 5, l = t & 31;
    float mx = -1e30f;
    for (int i = 0; i < 32; ++i) mx = fmaxf(mx, lt[(l + 32 * i) * NHEADS + h]);
    #pragma unroll
    for (int m = 16; m; m >>= 1) mx = fmaxf(mx, __shfl_xor(mx, m, 32));
    float sm = 0.0f;
    for (int i = 0; i < 32; ++i) sm += expf(lt[(l + 32 * i) * NHEADS + h] - mx);
    #pragma unroll
    for (int m = 16; m; m >>= 1) sm += __shfl_xor(sm, m, 32);
    const float inv = 1.0f / sm;
    for (int i = 0; i < 32; ++i) {
      const int key = l + 32 * i;
      lt[key * NHEADS + h] = expf(lt[key * NHEADS + h] - mx) * inv;
    }
  }
  __syncthreads();

  // -------- pass 2: ctx[h][j] = sum_k a[h][k] * pe[k][j]  (thread = dim j) --------
  {
    float cacc[NHEADS] = {0, 0, 0, 0, 0, 0, 0, 0};
    for (int key = 0; key < TWO_N; ++key) {
      const float v = peb[(size_t)key * DD + t];      // coalesced
      const float4 a0 = *(const float4*)&lt[key * NHEADS];      // uniform bcast
      const float4 a1 = *(const float4*)&lt[key * NHEADS + 4];
      cacc[0] += a0.x * v; cacc[1] += a0.y * v; cacc[2] += a0.z * v; cacc[3] += a0.w * v;
      cacc[4] += a1.x * v; cacc[5] += a1.y * v; cacc[6] += a1.z * v; cacc[7] += a1.w * v;
    }
    #pragma unroll
    for (int h = 0; h < NHEADS; ++h) ctx_sh[h * DD + t] = cacc[h];
  }
  __syncthreads();

  // -------- o1[t] = Wv[t] . ctx[t>>5] + bv[t]  (Wv rows = in_w[512..767]) --------
  {
    const float* wv = in_w + (size_t)(2 * DD + t) * DD;
    const float* cx = ctx_sh + (t >> 5) * DD;
    float o1 = in_b[2 * DD + t];
    for (int j = 0; j < DD; ++j) o1 += wv[j] * cx[j];
    o_sh[t] = o1;
  }
  __syncthreads();
  // -------- o2 = o1 @ out_w.T + out_b --------
  {
    const float* wr = out_w + (size_t)t * DD;
    float o2 = out_b[t];
    for (int j = 0; j < DD; ++j) o2 += wr[j] * o_sh[j];
    o2_sh[t] = o2;
  }
  __syncthreads();
  // -------- out = o2 @ W_fc.T + b_fc --------
  if (t < 6) {
    const float* wr = W_fc + (size_t)t * DD;
    float r = b_fc[t];
    for (int j = 0; j < DD; ++j) r += wr[j] * o2_sh[j];
    outp[b * 6 + t] = r;
  }
}

// ---------------------------------------------------------------------------
extern "C" void kernel_launch(void* const* d_in, const int* in_sizes, int n_in,
                              void* d_out, int out_size, void* d_ws, size_t ws_size,
                              hipStream_t stream) {
  const float* im0       = (const float*)d_in[0];
  const float* im1       = (const float*)d_in[1];
  const float* kpts0     = (const float*)d_in[2];
  const float* kpts1     = (const float*)d_in[3];
  const float* scores0   = (const float*)d_in[4];
  const float* scores1   = (const float*)d_in[5];
  const float* image_embs= (const float*)d_in[6];
  const int*   smatch    = (const int*)d_in[7];
  const float* ln1_g     = (const float*)d_in[8];
  const float* ln1_b     = (const float*)d_in[9];
  const float* W_pe      = (const float*)d_in[10];
  const float* b_pe      = (const float*)d_in[11];
  const float* ln2_g     = (const float*)d_in[12];
  const float* ln2_b     = (const float*)d_in[13];
  const float* W_proj    = (const float*)d_in[14];
  const float* b_proj    = (const float*)d_in[15];
  const float* in_w      = (const float*)d_in[16];
  const float* in_b      = (const float*)d_in[17];
  const float* out_w     = (const float*)d_in[18];
  const float* out_b     = (const float*)d_in[19];
  const float* W_fc      = (const float*)d_in[20];
  const float* b_fc      = (const float*)d_in[21];

  float* pe    = (float*)d_ws;
  float* u     = pe + PE_ELEMS;
  float* ubias = u + U_ELEMS;

  qproj_kernel<<<BB, 256, 0, stream>>>(image_embs, W_proj, b_proj, in_w, in_b,
                                       u, ubias);
  patch_pe_kernel<<<(BB * TWO_N) / 16, 256, 0, stream>>>(
      im0, im1, kpts0, kpts1, scores0, scores1, smatch,
      ln1_g, ln1_b, W_pe, b_pe, ln2_g, ln2_b, pe);
  attn_kernel<<<BB, 256, 0, stream>>>(pe, u, ubias, in_w, in_b, out_w, out_b,
                                      W_fc, b_fc, (float*)d_out);
}

// Round 2
// 562.528 us; speedup vs baseline: 2.4081x; 2.4081x over previous
//
#include <hip/hip_runtime.h>
#include <math.h>

#define BB 32
#define MM 2048
#define NN 512
#define PSZ 16
#define HH 640
#define WW 640
#define DD 256
#define DIMG_ 384
#define NHEADS 8
#define PD_ 768
#define TWO_N 1024
#define ROWS_TOT (BB * TWO_N)          // 32768 patch rows

typedef short bf16x8 __attribute__((ext_vector_type(8)));
typedef float f32x4  __attribute__((ext_vector_type(4)));

// ---- fp32 -> bf16 (RNE) helpers -------------------------------------------
__device__ __forceinline__ unsigned short f2bf(float x) {
  unsigned int u = __float_as_uint(x);
  u = (u + 0x7FFF + ((u >> 16) & 1)) >> 16;
  return (unsigned short)u;
}
__device__ __forceinline__ float bf2f(unsigned short h) {
  return __uint_as_float(((unsigned int)h) << 16);
}

// ---- async global->LDS (16B per lane, lds base must be wave-uniform) ------
__device__ __forceinline__ void gload_lds16(const void* g, void* l) {
  __builtin_amdgcn_global_load_lds(
      (const __attribute__((address_space(1))) void*)g,
      (__attribute__((address_space(3))) void*)l, 16, 0, 0);
}

// ---------------------------------------------------------------------------
// Kernel 1: q = embs @ W_proj.T + b_proj ; q2 = q @ Wq.T + bq ;
//           u[b,h,:] = Wk_h^T q2_h ; ubias[b,h] = q2_h . bk_h
// ---------------------------------------------------------------------------
__global__ __launch_bounds__(256) void qproj_kernel(
    const float* __restrict__ image_embs,
    const float* __restrict__ W_proj, const float* __restrict__ b_proj,
    const float* __restrict__ in_w,   const float* __restrict__ in_b,
    float* __restrict__ u_out, float* __restrict__ bias_out)
{
  __shared__ float q1[DD];
  __shared__ float q2[DD];
  const int t = threadIdx.x;
  const int b = blockIdx.x;

  {
    const float* emb = image_embs + (size_t)b * DIMG_;
    const float* wr  = W_proj + (size_t)t * DIMG_;
    float a = b_proj[t];
    for (int i = 0; i < DIMG_; ++i) a += emb[i] * wr[i];
    q1[t] = a;
  }
  __syncthreads();
  {
    const float* wr = in_w + (size_t)t * DD;
    float a = in_b[t];
    for (int i = 0; i < DD; ++i) a += q1[i] * wr[i];
    q2[t] = a;
  }
  __syncthreads();
  #pragma unroll
  for (int h = 0; h < NHEADS; ++h) {
    float s = 0.0f;
    #pragma unroll 8
    for (int i = 0; i < 32; ++i)
      s += q2[h * 32 + i] * in_w[(size_t)(DD + h * 32 + i) * DD + t];
    u_out[((size_t)b * NHEADS + h) * DD + t] = s;
  }
  if (t < NHEADS) {
    float s = 0.0f;
    for (int i = 0; i < 32; ++i) s += q2[t * 32 + i] * in_b[DD + t * 32 + i];
    bias_out[b * NHEADS + t] = s;
  }
}

// ---------------------------------------------------------------------------
// Kernel 2: W_pe (fp32 [255][768]) -> Whi/Wlo bf16 [256][768], row 255 = 0
// ---------------------------------------------------------------------------
__global__ __launch_bounds__(256) void wconv_kernel(
    const float* __restrict__ W_pe,
    unsigned short* __restrict__ Whi, unsigned short* __restrict__ Wlo)
{
  const int idx = blockIdx.x * 256 + threadIdx.x;   // 256*768 total
  const int row = idx / PD_;
  float v = (row < 255) ? W_pe[idx] : 0.0f;
  const unsigned short h = f2bf(v);
  Whi[idx] = h;
  Wlo[idx] = f2bf(v - bf2f(h));
}

// ---------------------------------------------------------------------------
// Kernel 3: patch extraction + LN1 -> Ahi/Alo bf16 [32768][768] + score[row]
// 16 patches per block, 256 threads.
// ---------------------------------------------------------------------------
__global__ __launch_bounds__(256) void extract_kernel(
    const float* __restrict__ im0, const float* __restrict__ im1,
    const float* __restrict__ kpts0, const float* __restrict__ kpts1,
    const float* __restrict__ scores0, const float* __restrict__ scores1,
    const int*   __restrict__ sorted_matches,
    const float* __restrict__ ln1_g, const float* __restrict__ ln1_b,
    unsigned short* __restrict__ Ahi, unsigned short* __restrict__ Alo,
    float* __restrict__ score_all)
{
  __shared__ __align__(16) float A[16][PD_];   // 49152 B
  __shared__ int   sx0[16], sy0[16], svalid[16];
  __shared__ float smu[16], srs[16];

  const int t   = threadIdx.x;
  const int blk = blockIdx.x;
  const int b      = blk >> 6;            // 64 blocks per batch (1024/16)
  const int n2base = (blk & 63) << 4;     // all 16 patches same side
  const bool side1 = (n2base >= NN);
  const float* img  = side1 ? im1 : im0;
  const float* kpts = side1 ? kpts1 : kpts0;
  const float* scrs = side1 ? scores1 : scores0;

  if (t < 16) {
    const int n2 = n2base + t;
    const int n  = side1 ? (n2 - NN) : n2;
    const int m0 = sorted_matches[((size_t)b * NN + n) * 2 + 0];
    const int m1 = sorted_matches[((size_t)b * NN + n) * 2 + 1];
    const int valid = (m1 > -1) ? 1 : 0;
    int midx = side1 ? m1 : m0;
    midx = min(max(midx, 0), MM - 1);
    const float kx = kpts[((size_t)b * MM + midx) * 2 + 0];
    const float ky = kpts[((size_t)b * MM + midx) * 2 + 1];
    const int cx = (int)rintf(kx);        // round-half-even == jnp.round
    const int cy = (int)rintf(ky);
    sx0[t] = min(max(cx - 8, 0), WW - PSZ);
    sy0[t] = min(max(cy - 8, 0), HH - PSZ);
    svalid[t] = valid;
    score_all[blk * 16 + t] = valid ? scrs[(size_t)b * MM + midx] : 0.0f;
  }
  __syncthreads();

  const size_t imb = (size_t)b * 3 * HH * WW;
  #pragma unroll 4
  for (int i = 0; i < 48; ++i) {
    const int idx = i * 256 + t;
    const int p   = idx / PD_;
    const int rem = idx - p * PD_;
    const int c   = rem >> 8;
    const int r2  = rem & 255;
    const int py  = r2 >> 4;
    const int px  = r2 & 15;
    float v = -1.0f;
    if (svalid[p]) {
      const float pix = img[imb + ((size_t)c * HH + (sy0[p] + py)) * WW + sx0[p] + px];
      v = fminf(fmaxf(pix, 0.0f), 1.0f);
    }
    A[p][rem] = v;
  }
  __syncthreads();

  {
    const int p = t >> 4, j = t & 15;
    float s = 0.0f, ss = 0.0f;
    #pragma unroll 8
    for (int i = 0; i < 48; ++i) { const float v = A[p][j + 16 * i]; s += v; ss += v * v; }
    #pragma unroll
    for (int m = 8; m; m >>= 1) { s += __shfl_xor(s, m, 16); ss += __shfl_xor(ss, m, 16); }
    if (j == 0) {
      const float mu  = s * (1.0f / 768.0f);
      const float var = ss * (1.0f / 768.0f) - mu * mu;
      smu[p] = mu;
      srs[p] = 1.0f / sqrtf(var + 1e-5f);
    }
  }
  __syncthreads();

  // normalize + split to bf16 hi/lo, write coalesced
  #pragma unroll 4
  for (int i = 0; i < 48; ++i) {
    const int idx = i * 256 + t;
    const int p   = idx / PD_;
    const int rem = idx - p * PD_;
    const float y = (A[p][rem] - smu[p]) * srs[p] * ln1_g[rem] + ln1_b[rem];
    const size_t o = (size_t)(blk * 16 + p) * PD_ + rem;
    const unsigned short h = f2bf(y);
    Ahi[o] = h;
    Alo[o] = f2bf(y - bf2f(h));
  }
}

// ---------------------------------------------------------------------------
// Kernel 4: e[32768][256] = A[32768][768] @ W.T  via split-bf16 MFMA
// 128x128 block tile, BK=32, 4 waves (each 64x64), grid = 256 mtiles x 2 ntiles
// ---------------------------------------------------------------------------
__global__ __launch_bounds__(256) void gemm_pe_kernel(
    const unsigned short* __restrict__ Ahi, const unsigned short* __restrict__ Alo,
    const unsigned short* __restrict__ Whi, const unsigned short* __restrict__ Wlo,
    float* __restrict__ e)
{
  __shared__ __align__(16) unsigned short As[2][128][32];  // hi, lo : 16 KB
  __shared__ __align__(16) unsigned short Bs[2][128][32];  // hi, lo : 16 KB

  const int t  = threadIdx.x;
  const int w  = t >> 6;
  const int L  = t & 63;
  const int mt = blockIdx.x >> 1;
  const int nt = blockIdx.x & 1;

  f32x4 acc[4][4];
  #pragma unroll
  for (int i = 0; i < 4; ++i)
    #pragma unroll
    for (int j = 0; j < 4; ++j) acc[i][j] = (f32x4){0.f, 0.f, 0.f, 0.f};

  // ---- staging role of this wave ----
  const unsigned short* src;
  unsigned short* dstbase;
  long rowbase;
  if      (w == 0) { src = Ahi; dstbase = &As[0][0][0]; rowbase = (long)mt * 128; }
  else if (w == 1) { src = Alo; dstbase = &As[1][0][0]; rowbase = (long)mt * 128; }
  else if (w == 2) { src = Whi; dstbase = &Bs[0][0][0]; rowbase = (long)nt * 128; }
  else             { src = Wlo; dstbase = &Bs[1][0][0]; rowbase = (long)nt * 128; }
  const int rr   = L >> 2;                       // row within 16-row chunk
  const int q_st = (L & 3) ^ ((L >> 4) & 3);     // XOR-swizzled k-quad to fetch

  // ---- fragment addressing (same swizzle on read) ----
  const int lane_m = L & 15;
  const int quad   = L >> 4;
  const int swz    = quad ^ (lane_m >> 2);       // slot holding wanted quad

  const unsigned short* As0 = &As[0][0][0];
  const unsigned short* As1 = &As[1][0][0];
  const unsigned short* Bs0 = &Bs[0][0][0];
  const unsigned short* Bs1 = &Bs[1][0][0];
  const int am0 = (w >> 1) * 64;                 // wave tile origin (rows)
  const int bn0 = (w & 1) * 64;                  // wave tile origin (cols)

  for (int ks = 0; ks < PD_ / 32; ++ks) {
    const int k0 = ks * 32;
    __syncthreads();                              // LDS free to overwrite
    {
      const unsigned short* gs = src + (rowbase + rr) * (long)PD_ + k0 + q_st * 8;
      #pragma unroll
      for (int c = 0; c < 8; ++c)                 // 8 chunks x 16 rows
        gload_lds16(gs + (long)c * 16 * PD_, dstbase + c * 512);
    }
    __syncthreads();                              // staging complete

    bf16x8 ah[4], al[4], bh[4], bl[4];
    #pragma unroll
    for (int i = 0; i < 4; ++i) {
      const int offa = (am0 + i * 16 + lane_m) * 32 + swz * 8;
      ah[i] = *(const bf16x8*)(As0 + offa);
      al[i] = *(const bf16x8*)(As1 + offa);
      const int offb = (bn0 + i * 16 + lane_m) * 32 + swz * 8;
      bh[i] = *(const bf16x8*)(Bs0 + offb);
      bl[i] = *(const bf16x8*)(Bs1 + offb);
    }
    #pragma unroll
    for (int i = 0; i < 4; ++i)
      #pragma unroll
      for (int j = 0; j < 4; ++j) {
        acc[i][j] = __builtin_amdgcn_mfma_f32_16x16x32_bf16(ah[i], bh[j], acc[i][j], 0, 0, 0);
        acc[i][j] = __builtin_amdgcn_mfma_f32_16x16x32_bf16(ah[i], bl[j], acc[i][j], 0, 0, 0);
        acc[i][j] = __builtin_amdgcn_mfma_f32_16x16x32_bf16(al[i], bh[j], acc[i][j], 0, 0, 0);
      }
  }

  // epilogue: C/D layout col=lane&15, row=quad*4+reg  [verified m89/m91]
  const long grow0 = (long)mt * 128 + am0;
  const int  gcol0 = nt * 128 + bn0;
  #pragma unroll
  for (int i = 0; i < 4; ++i)
    #pragma unroll
    for (int j = 0; j < 4; ++j)
      #pragma unroll
      for (int v = 0; v < 4; ++v) {
        const long row = grow0 + i * 16 + quad * 4 + v;
        const int  col = gcol0 + j * 16 + lane_m;
        e[row * DD + col] = acc[i][j][v];
      }
}

// ---------------------------------------------------------------------------
// Kernel 5: per-row +b_pe, LN2, append score -> pe (in place over e),
//           then logits lt[b][key][h] = (pe_row . u[b,h] + ubias) * scale
// 8 rows per block, 32 lanes per row.
// ---------------------------------------------------------------------------
__global__ __launch_bounds__(256) void ln2_logits_kernel(
    float* epe,                               // in: e, out: pe (in place)
    const float* __restrict__ b_pe,
    const float* __restrict__ ln2_g, const float* __restrict__ ln2_b,
    const float* __restrict__ score_all,
    const float* __restrict__ u, const float* __restrict__ ubias,
    float* __restrict__ lt)
{
  const int t = threadIdx.x;
  const int g = t >> 5, l = t & 31;
  const long row = (long)blockIdx.x * 8 + g;
  const int  b   = (int)(row >> 10);
  float* er = epe + row * DD;

  float x[8];
  float s = 0.0f, ss = 0.0f;
  #pragma unroll
  for (int j = 0; j < 8; ++j) {
    const int c = l + 32 * j;
    float v = er[c];
    if (c < 255) { v += b_pe[c]; s += v; ss += v * v; }
    x[j] = v;
  }
  #pragma unroll
  for (int m = 16; m; m >>= 1) { s += __shfl_xor(s, m, 32); ss += __shfl_xor(ss, m, 32); }
  const float mu  = s * (1.0f / 255.0f);
  const float var = ss * (1.0f / 255.0f) - mu * mu;
  const float rs  = 1.0f / sqrtf(var + 1e-5f);

  float y[8];
  #pragma unroll
  for (int j = 0; j < 8; ++j) {
    const int c = l + 32 * j;
    y[j] = (c < 255) ? (x[j] - mu) * rs * ln2_g[c] + ln2_b[c] : score_all[row];
    er[c] = y[j];
  }

  // logits: 8 heads, u rows are wave-semi-uniform small reads (L1-resident)
  const float* ub = u + (size_t)b * NHEADS * DD;
  float d[NHEADS] = {0, 0, 0, 0, 0, 0, 0, 0};
  #pragma unroll
  for (int j = 0; j < 8; ++j) {
    const int c = l + 32 * j;
    #pragma unroll
    for (int h = 0; h < NHEADS; ++h) d[h] += y[j] * ub[h * DD + c];
  }
  #pragma unroll
  for (int h = 0; h < NHEADS; ++h) {
    #pragma unroll
    for (int m = 16; m; m >>= 1) d[h] += __shfl_xor(d[h], m, 32);
  }
  if (l == 0) {
    const float sc = 0.17677669529663687f;     // 1/sqrt(32)
    #pragma unroll
    for (int h = 0; h < NHEADS; ++h)
      lt[row * NHEADS + h] = (d[h] + ubias[b * NHEADS + h]) * sc;
  }
}

// ---------------------------------------------------------------------------
// Kernel 6: softmax over 1024 keys per (b,h), probs in place
// ---------------------------------------------------------------------------
__global__ __launch_bounds__(256) void softmax_kernel(float* __restrict__ lt)
{
  const int b = blockIdx.x, t = threadIdx.x;
  const int h = t >> 5, l = t & 31;
  float* base = lt + (size_t)b * TWO_N * NHEADS + h;
  float v[32];
  float mx = -1e30f;
  #pragma unroll 8
  for (int i = 0; i < 32; ++i) { v[i] = base[(l + 32 * i) * NHEADS]; mx = fmaxf(mx, v[i]); }
  #pragma unroll
  for (int m = 16; m; m >>= 1) mx = fmaxf(mx, __shfl_xor(mx, m, 32));
  float sm = 0.0f;
  #pragma unroll 8
  for (int i = 0; i < 32; ++i) { v[i] = expf(v[i] - mx); sm += v[i]; }
  #pragma unroll
  for (int m = 16; m; m >>= 1) sm += __shfl_xor(sm, m, 32);
  const float inv = 1.0f / sm;
  #pragma unroll 8
  for (int i = 0; i < 32; ++i) base[(l + 32 * i) * NHEADS] = v[i] * inv;
}

// ---------------------------------------------------------------------------
// Kernel 7: partial ctx over 128-key chunks: ctxp[b][ch][h][256]
// ---------------------------------------------------------------------------
__global__ __launch_bounds__(256) void ctx_kernel(
    const float* __restrict__ pe, const float* __restrict__ lt,
    float* __restrict__ ctxp)
{
  const int b = blockIdx.x, ch = blockIdx.y, t = threadIdx.x;
  const float* peb = pe + ((size_t)b * TWO_N + ch * 128) * DD;
  const float* ab  = lt + ((size_t)b * TWO_N + ch * 128) * NHEADS;
  float acc[NHEADS] = {0, 0, 0, 0, 0, 0, 0, 0};
  for (int k = 0; k < 128; ++k) {
    const float v = peb[(size_t)k * DD + t];           // coalesced
    const float4 a0 = *(const float4*)(ab + k * NHEADS);
    const float4 a1 = *(const float4*)(ab + k * NHEADS + 4);
    acc[0] += a0.x * v; acc[1] += a0.y * v; acc[2] += a0.z * v; acc[3] += a0.w * v;
    acc[4] += a1.x * v; acc[5] += a1.y * v; acc[6] += a1.z * v; acc[7] += a1.w * v;
  }
  #pragma unroll
  for (int h = 0; h < NHEADS; ++h)
    ctxp[(((size_t)b * 8 + ch) * NHEADS + h) * DD + t] = acc[h];
}

// ---------------------------------------------------------------------------
// Kernel 8: reduce ctx partials + Wv + out_w + W_fc head
// ---------------------------------------------------------------------------
__global__ __launch_bounds__(256) void final_kernel(
    const float* __restrict__ ctxp,
    const float* __restrict__ in_w,  const float* __restrict__ in_b,
    const float* __restrict__ out_w, const float* __restrict__ out_b,
    const float* __restrict__ W_fc,  const float* __restrict__ b_fc,
    float* __restrict__ outp)
{
  __shared__ float ctx_sh[NHEADS * DD];
  __shared__ float o_sh[DD], o2_sh[DD];
  const int t = threadIdx.x;
  const int b = blockIdx.x;

  #pragma unroll
  for (int h = 0; h < NHEADS; ++h) {
    float s = 0.0f;
    #pragma unroll
    for (int ch = 0; ch < 8; ++ch)
      s += ctxp[(((size_t)b * 8 + ch) * NHEADS + h) * DD + t];
    ctx_sh[h * DD + t] = s;
  }
  __syncthreads();
  {
    const float* wv = in_w + (size_t)(2 * DD + t) * DD;
    const float* cx = ctx_sh + (t >> 5) * DD;
    float o1 = in_b[2 * DD + t];
    for (int j = 0; j < DD; ++j) o1 += wv[j] * cx[j];
    o_sh[t] = o1;
  }
  __syncthreads();
  {
    const float* wr = out_w + (size_t)t * DD;
    float o2 = out_b[t];
    for (int j = 0; j < DD; ++j) o2 += wr[j] * o_sh[j];
    o2_sh[t] = o2;
  }
  __syncthreads();
  if (t < 6) {
    const float* wr = W_fc + (size_t)t * DD;
    float r = b_fc[t];
    for (int j = 0; j < DD; ++j) r += wr[j] * o2_sh[j];
    outp[b * 6 + t] = r;
  }
}

// ---------------------------------------------------------------------------
extern "C" void kernel_launch(void* const* d_in, const int* in_sizes, int n_in,
                              void* d_out, int out_size, void* d_ws, size_t ws_size,
                              hipStream_t stream) {
  const float* im0       = (const float*)d_in[0];
  const float* im1       = (const float*)d_in[1];
  const float* kpts0     = (const float*)d_in[2];
  const float* kpts1     = (const float*)d_in[3];
  const float* scores0   = (const float*)d_in[4];
  const float* scores1   = (const float*)d_in[5];
  const float* image_embs= (const float*)d_in[6];
  const int*   smatch    = (const int*)d_in[7];
  const float* ln1_g     = (const float*)d_in[8];
  const float* ln1_b     = (const float*)d_in[9];
  const float* W_pe      = (const float*)d_in[10];
  const float* b_pe      = (const float*)d_in[11];
  const float* ln2_g     = (const float*)d_in[12];
  const float* ln2_b     = (const float*)d_in[13];
  const float* W_proj    = (const float*)d_in[14];
  const float* b_proj    = (const float*)d_in[15];
  const float* in_w      = (const float*)d_in[16];
  const float* in_b      = (const float*)d_in[17];
  const float* out_w     = (const float*)d_in[18];
  const float* out_b     = (const float*)d_in[19];
  const float* W_fc      = (const float*)d_in[20];
  const float* b_fc      = (const float*)d_in[21];

  // ---- workspace layout (bytes) ----
  char* ws = (char*)d_ws;
  size_t off = 0;
  float* epe   = (float*)(ws + off); off += (size_t)ROWS_TOT * DD * 4;        // 32 MB
  float* u     = (float*)(ws + off); off += (size_t)BB * NHEADS * DD * 4;     // 256 KB
  float* ubias = (float*)(ws + off); off += (size_t)BB * NHEADS * 4;
  off = (off + 1023) & ~(size_t)1023;
  float* score = (float*)(ws + off); off += (size_t)ROWS_TOT * 4;             // 128 KB
  float* lt    = (float*)(ws + off); off += (size_t)BB * TWO_N * NHEADS * 4;  // 1 MB
  float* ctxp  = (float*)(ws + off); off += (size_t)BB * 8 * NHEADS * DD * 4; // 2 MB
  unsigned short* Whi = (unsigned short*)(ws + off); off += (size_t)256 * PD_ * 2;
  unsigned short* Wlo = (unsigned short*)(ws + off); off += (size_t)256 * PD_ * 2;
  off = (off + 1023) & ~(size_t)1023;
  unsigned short* Ahi = (unsigned short*)(ws + off); off += (size_t)ROWS_TOT * PD_ * 2; // 50 MB
  unsigned short* Alo = (unsigned short*)(ws + off); off += (size_t)ROWS_TOT * PD_ * 2; // 50 MB

  qproj_kernel<<<BB, 256, 0, stream>>>(image_embs, W_proj, b_proj, in_w, in_b,
                                       u, ubias);
  wconv_kernel<<<(256 * PD_) / 256, 256, 0, stream>>>(W_pe, Whi, Wlo);
  extract_kernel<<<ROWS_TOT / 16, 256, 0, stream>>>(
      im0, im1, kpts0, kpts1, scores0, scores1, smatch,
      ln1_g, ln1_b, Ahi, Alo, score);
  gemm_pe_kernel<<<(ROWS_TOT / 128) * 2, 256, 0, stream>>>(Ahi, Alo, Whi, Wlo, epe);
  ln2_logits_kernel<<<ROWS_TOT / 8, 256, 0, stream>>>(
      epe, b_pe, ln2_g, ln2_b, score, u, ubias, lt);
  softmax_kernel<<<BB, 256, 0, stream>>>(lt);
  ctx_kernel<<<dim3(BB, 8), 256, 0, stream>>>(epe, lt, ctxp);
  final_kernel<<<BB, 256, 0, stream>>>(ctxp, in_w, in_b, out_w, out_b,
                                       W_fc, b_fc, (float*)d_out);
}

// Round 3
// 494.903 us; speedup vs baseline: 2.7371x; 1.1366x over previous
//
#include <hip/hip_runtime.h>
#include <math.h>

#define BB 32
#define MM 2048
#define NN 512
#define PSZ 16
#define HH 640
#define WW 640
#define DD 256
#define DIMG_ 384
#define NHEADS 8
#define PD_ 768
#define TWO_N 1024
#define ROWS_TOT (BB * TWO_N)          // 32768 patch rows

typedef short bf16x8 __attribute__((ext_vector_type(8)));
typedef float f32x4  __attribute__((ext_vector_type(4)));

// ---- fp32 -> bf16 (RNE) helpers -------------------------------------------
__device__ __forceinline__ unsigned short f2bf(float x) {
  unsigned int u = __float_as_uint(x);
  u = (u + 0x7FFF + ((u >> 16) & 1)) >> 16;
  return (unsigned short)u;
}
__device__ __forceinline__ float bf2f(unsigned short h) {
  return __uint_as_float(((unsigned int)h) << 16);
}

// ---- async global->LDS (16B per lane, lds base must be wave-uniform) ------
__device__ __forceinline__ void gload_lds16(const void* g, void* l) {
  __builtin_amdgcn_global_load_lds(
      (const __attribute__((address_space(1))) void*)g,
      (__attribute__((address_space(3))) void*)l, 16, 0, 0);
}

// ---------------------------------------------------------------------------
// Kernel 1 (fused prep): blocks 0..767 convert W_pe -> Whi/Wlo bf16;
// blocks 768..799 do the q-side projections:
//   q = embs @ W_proj.T + b_proj ; q2 = q @ Wq.T + bq ;
//   u[b,h,:] = Wk_h^T q2_h ; ubias[b,h] = q2_h . bk_h
// ---------------------------------------------------------------------------
__global__ __launch_bounds__(256) void prep_kernel(
    const float* __restrict__ W_pe,
    unsigned short* __restrict__ Whi, unsigned short* __restrict__ Wlo,
    const float* __restrict__ image_embs,
    const float* __restrict__ W_proj, const float* __restrict__ b_proj,
    const float* __restrict__ in_w,   const float* __restrict__ in_b,
    float* __restrict__ u_out, float* __restrict__ bias_out)
{
  __shared__ float q1[DD];
  __shared__ float q2[DD];
  const int t = threadIdx.x;

  if (blockIdx.x < 768) {                 // ---- W conversion ----
    const int idx = blockIdx.x * 256 + t; // 256*768 total
    const int row = idx / PD_;
    float v = (row < 255) ? W_pe[idx] : 0.0f;
    const unsigned short h = f2bf(v);
    Whi[idx] = h;
    Wlo[idx] = f2bf(v - bf2f(h));
    return;
  }

  const int b = blockIdx.x - 768;         // ---- q projections ----
  {
    const float4* emb = (const float4*)(image_embs + (size_t)b * DIMG_);
    const float4* wr  = (const float4*)(W_proj + (size_t)t * DIMG_);
    float a = b_proj[t];
    #pragma unroll 4
    for (int i = 0; i < DIMG_ / 4; ++i) {
      const float4 e4 = emb[i], w4 = wr[i];
      a += e4.x * w4.x + e4.y * w4.y + e4.z * w4.z + e4.w * w4.w;
    }
    q1[t] = a;
  }
  __syncthreads();
  {
    const float4* wr = (const float4*)(in_w + (size_t)t * DD);
    const float4* qq = (const float4*)q1;
    float a = in_b[t];
    #pragma unroll 4
    for (int i = 0; i < DD / 4; ++i) {
      const float4 q4 = qq[i], w4 = wr[i];
      a += q4.x * w4.x + q4.y * w4.y + q4.z * w4.z + q4.w * w4.w;
    }
    q2[t] = a;
  }
  __syncthreads();
  #pragma unroll
  for (int h = 0; h < NHEADS; ++h) {
    float s = 0.0f;
    #pragma unroll 8
    for (int i = 0; i < 32; ++i)
      s += q2[h * 32 + i] * in_w[(size_t)(DD + h * 32 + i) * DD + t];
    u_out[((size_t)b * NHEADS + h) * DD + t] = s;
  }
  if (t < NHEADS) {
    float s = 0.0f;
    for (int i = 0; i < 32; ++i) s += q2[t * 32 + i] * in_b[DD + t * 32 + i];
    bias_out[b * NHEADS + t] = s;
  }
}

// ---------------------------------------------------------------------------
// Kernel 2: patch extraction + LN1 -> Ahi/Alo bf16 [32768][768] + score[row]
// One WAVE per patch, zero LDS. Lane L holds pixels {2L,2L+1} + 128*j, j<6.
// ---------------------------------------------------------------------------
__global__ __launch_bounds__(256) void extract_kernel(
    const float* __restrict__ im0, const float* __restrict__ im1,
    const float* __restrict__ kpts0, const float* __restrict__ kpts1,
    const float* __restrict__ scores0, const float* __restrict__ scores1,
    const int*   __restrict__ sorted_matches,
    const float* __restrict__ ln1_g, const float* __restrict__ ln1_b,
    unsigned short* __restrict__ Ahi, unsigned short* __restrict__ Alo,
    float* __restrict__ score_all)
{
  const int t  = threadIdx.x;
  const int L  = t & 63;
  const long gp = (long)blockIdx.x * 4 + (t >> 6);   // global patch row
  const int b   = (int)(gp >> 10);
  const int n2  = (int)(gp & 1023);
  const bool side1 = (n2 >= NN);
  const float* img  = side1 ? im1 : im0;
  const float* kpts = side1 ? kpts1 : kpts0;
  const float* scrs = side1 ? scores1 : scores0;

  // per-patch setup: all lanes compute identically (same-address loads bcast)
  const int n  = side1 ? (n2 - NN) : n2;
  const int m0 = sorted_matches[((size_t)b * NN + n) * 2 + 0];
  const int m1 = sorted_matches[((size_t)b * NN + n) * 2 + 1];
  const bool valid = (m1 > -1);
  int midx = side1 ? m1 : m0;
  midx = min(max(midx, 0), MM - 1);
  const float kx = kpts[((size_t)b * MM + midx) * 2 + 0];
  const float ky = kpts[((size_t)b * MM + midx) * 2 + 1];
  const int x0 = min(max((int)rintf(kx) - 8, 0), WW - PSZ);
  const int y0 = min(max((int)rintf(ky) - 8, 0), HH - PSZ);

  float v[12];
  if (valid) {
    const size_t imb = (size_t)b * 3 * HH * WW;
    const int px = (2 * L) & 15;
    #pragma unroll
    for (int j = 0; j < 6; ++j) {
      const int p0 = 2 * L + 128 * j;
      const int c  = p0 >> 8;
      const int py = (p0 >> 4) & 15;
      const float* rp = img + imb + ((size_t)c * HH + y0 + py) * WW + x0 + px;
      v[2 * j]     = fminf(fmaxf(rp[0], 0.0f), 1.0f);
      v[2 * j + 1] = fminf(fmaxf(rp[1], 0.0f), 1.0f);
    }
  } else {
    #pragma unroll
    for (int i = 0; i < 12; ++i) v[i] = -1.0f;
  }

  // LN1 stats: wave-wide reduce
  float s = 0.0f, ss = 0.0f;
  #pragma unroll
  for (int i = 0; i < 12; ++i) { s += v[i]; ss += v[i] * v[i]; }
  #pragma unroll
  for (int m = 32; m; m >>= 1) { s += __shfl_xor(s, m); ss += __shfl_xor(ss, m); }
  const float mu  = s * (1.0f / 768.0f);
  const float var = ss * (1.0f / 768.0f) - mu * mu;
  const float rs  = 1.0f / sqrtf(var + 1e-5f);

  // normalize + split bf16, packed dword stores
  unsigned int* AhiW = (unsigned int*)(Ahi + gp * PD_);
  unsigned int* AloW = (unsigned int*)(Alo + gp * PD_);
  #pragma unroll
  for (int j = 0; j < 6; ++j) {
    const int p0 = 2 * L + 128 * j;
    const float y0e = (v[2 * j]     - mu) * rs * ln1_g[p0]     + ln1_b[p0];
    const float y1e = (v[2 * j + 1] - mu) * rs * ln1_g[p0 + 1] + ln1_b[p0 + 1];
    const unsigned short h0 = f2bf(y0e), h1 = f2bf(y1e);
    AhiW[p0 >> 1] = (unsigned int)h0 | ((unsigned int)h1 << 16);
    const unsigned short l0 = f2bf(y0e - bf2f(h0));
    const unsigned short l1 = f2bf(y1e - bf2f(h1));
    AloW[p0 >> 1] = (unsigned int)l0 | ((unsigned int)l1 << 16);
  }
  if (L == 0) {
    score_all[gp] = valid ? scrs[(size_t)b * MM + midx] : 0.0f;
  }
}

// ---------------------------------------------------------------------------
// Kernel 3: e[32768][256] = A[32768][768] @ W.T  via split-bf16 MFMA
// 128x128 block tile, BK=32, 4 waves (each 64x64).
// Block swizzle: ntile-pair of the same mtile lands on the same XCD (ids
// differing by 8 under round-robin %8) so the 2nd A read hits that XCD's L2.
// ---------------------------------------------------------------------------
__global__ __launch_bounds__(256) void gemm_pe_kernel(
    const unsigned short* __restrict__ Ahi, const unsigned short* __restrict__ Alo,
    const unsigned short* __restrict__ Whi, const unsigned short* __restrict__ Wlo,
    float* __restrict__ e)
{
  __shared__ __align__(16) unsigned short As[2][128][32];  // hi, lo : 16 KB
  __shared__ __align__(16) unsigned short Bs[2][128][32];  // hi, lo : 16 KB

  const int t  = threadIdx.x;
  const int w  = t >> 6;
  const int L  = t & 63;
  const int id = blockIdx.x;
  const int nt = (id >> 3) & 1;
  const int mt = ((id >> 4) << 3) | (id & 7);

  f32x4 acc[4][4];
  #pragma unroll
  for (int i = 0; i < 4; ++i)
    #pragma unroll
    for (int j = 0; j < 4; ++j) acc[i][j] = (f32x4){0.f, 0.f, 0.f, 0.f};

  // ---- staging role of this wave ----
  const unsigned short* src;
  unsigned short* dstbase;
  long rowbase;
  if      (w == 0) { src = Ahi; dstbase = &As[0][0][0]; rowbase = (long)mt * 128; }
  else if (w == 1) { src = Alo; dstbase = &As[1][0][0]; rowbase = (long)mt * 128; }
  else if (w == 2) { src = Whi; dstbase = &Bs[0][0][0]; rowbase = (long)nt * 128; }
  else             { src = Wlo; dstbase = &Bs[1][0][0]; rowbase = (long)nt * 128; }
  const int rr   = L >> 2;                       // row within 16-row chunk
  const int q_st = (L & 3) ^ ((L >> 4) & 3);     // XOR-swizzled k-quad to fetch

  // ---- fragment addressing (same swizzle on read) ----
  const int lane_m = L & 15;
  const int quad   = L >> 4;
  const int swz    = quad ^ (lane_m >> 2);       // slot holding wanted quad

  const unsigned short* As0 = &As[0][0][0];
  const unsigned short* As1 = &As[1][0][0];
  const unsigned short* Bs0 = &Bs[0][0][0];
  const unsigned short* Bs1 = &Bs[1][0][0];
  const int am0 = (w >> 1) * 64;                 // wave tile origin (rows)
  const int bn0 = (w & 1) * 64;                  // wave tile origin (cols)

  for (int ks = 0; ks < PD_ / 32; ++ks) {
    const int k0 = ks * 32;
    __syncthreads();                              // LDS free to overwrite
    {
      const unsigned short* gs = src + (rowbase + rr) * (long)PD_ + k0 + q_st * 8;
      #pragma unroll
      for (int c = 0; c < 8; ++c)                 // 8 chunks x 16 rows
        gload_lds16(gs + (long)c * 16 * PD_, dstbase + c * 512);
    }
    __syncthreads();                              // staging complete

    bf16x8 ah[4], al[4], bh[4], bl[4];
    #pragma unroll
    for (int i = 0; i < 4; ++i) {
      const int offa = (am0 + i * 16 + lane_m) * 32 + swz * 8;
      ah[i] = *(const bf16x8*)(As0 + offa);
      al[i] = *(const bf16x8*)(As1 + offa);
      const int offb = (bn0 + i * 16 + lane_m) * 32 + swz * 8;
      bh[i] = *(const bf16x8*)(Bs0 + offb);
      bl[i] = *(const bf16x8*)(Bs1 + offb);
    }
    #pragma unroll
    for (int i = 0; i < 4; ++i)
      #pragma unroll
      for (int j = 0; j < 4; ++j) {
        acc[i][j] = __builtin_amdgcn_mfma_f32_16x16x32_bf16(ah[i], bh[j], acc[i][j], 0, 0, 0);
        acc[i][j] = __builtin_amdgcn_mfma_f32_16x16x32_bf16(ah[i], bl[j], acc[i][j], 0, 0, 0);
        acc[i][j] = __builtin_amdgcn_mfma_f32_16x16x32_bf16(al[i], bh[j], acc[i][j], 0, 0, 0);
      }
  }

  // epilogue: C/D layout col=lane&15, row=quad*4+reg  [verified m89/m91]
  const long grow0 = (long)mt * 128 + am0;
  const int  gcol0 = nt * 128 + bn0;
  #pragma unroll
  for (int i = 0; i < 4; ++i)
    #pragma unroll
    for (int j = 0; j < 4; ++j)
      #pragma unroll
      for (int v = 0; v < 4; ++v) {
        const long row = grow0 + i * 16 + quad * 4 + v;
        const int  col = gcol0 + j * 16 + lane_m;
        e[row * DD + col] = acc[i][j][v];
      }
}

// ---------------------------------------------------------------------------
// Kernel 4: per-row +b_pe, LN2, append score -> pe (in place over e),
//           then logits lt[b][key][h] = (pe_row . u[b,h] + ubias) * scale
// 8 rows per block, 32 lanes per row.
// ---------------------------------------------------------------------------
__global__ __launch_bounds__(256) void ln2_logits_kernel(
    float* epe,                               // in: e, out: pe (in place)
    const float* __restrict__ b_pe,
    const float* __restrict__ ln2_g, const float* __restrict__ ln2_b,
    const float* __restrict__ score_all,
    const float* __restrict__ u, const float* __restrict__ ubias,
    float* __restrict__ lt)
{
  const int t = threadIdx.x;
  const int g = t >> 5, l = t & 31;
  const long row = (long)blockIdx.x * 8 + g;
  const int  b   = (int)(row >> 10);
  float* er = epe + row * DD;

  float x[8];
  float s = 0.0f, ss = 0.0f;
  #pragma unroll
  for (int j = 0; j < 8; ++j) {
    const int c = l + 32 * j;
    float v = er[c];
    if (c < 255) { v += b_pe[c]; s += v; ss += v * v; }
    x[j] = v;
  }
  #pragma unroll
  for (int m = 16; m; m >>= 1) { s += __shfl_xor(s, m, 32); ss += __shfl_xor(ss, m, 32); }
  const float mu  = s * (1.0f / 255.0f);
  const float var = ss * (1.0f / 255.0f) - mu * mu;
  const float rs  = 1.0f / sqrtf(var + 1e-5f);

  float y[8];
  #pragma unroll
  for (int j = 0; j < 8; ++j) {
    const int c = l + 32 * j;
    y[j] = (c < 255) ? (x[j] - mu) * rs * ln2_g[c] + ln2_b[c] : score_all[row];
    er[c] = y[j];
  }

  // logits: 8 heads
  const float* ub = u + (size_t)b * NHEADS * DD;
  float d[NHEADS] = {0, 0, 0, 0, 0, 0, 0, 0};
  #pragma unroll
  for (int j = 0; j < 8; ++j) {
    const int c = l + 32 * j;
    #pragma unroll
    for (int h = 0; h < NHEADS; ++h) d[h] += y[j] * ub[h * DD + c];
  }
  #pragma unroll
  for (int h = 0; h < NHEADS; ++h) {
    #pragma unroll
    for (int m = 16; m; m >>= 1) d[h] += __shfl_xor(d[h], m, 32);
  }
  if (l == 0) {
    const float sc = 0.17677669529663687f;     // 1/sqrt(32)
    #pragma unroll
    for (int h = 0; h < NHEADS; ++h)
      lt[row * NHEADS + h] = (d[h] + ubias[b * NHEADS + h]) * sc;
  }
}

// ---------------------------------------------------------------------------
// Kernel 5: fused softmax + partial ctx over 128-key chunks.
// Each block redundantly computes its batch's softmax (L2-resident logits)
// into LDS, then accumulates ctxp[b][ch][h][256].
// ---------------------------------------------------------------------------
__global__ __launch_bounds__(256) void ctx_kernel(
    const float* __restrict__ pe, const float* __restrict__ lt,
    float* __restrict__ ctxp)
{
  __shared__ __align__(16) float pr[TWO_N][NHEADS];   // 32 KB probs
  const int b = blockIdx.x, ch = blockIdx.y, t = threadIdx.x;

  // softmax for all 1024 keys of batch b (h = t>>5 head, 32 lanes per head)
  {
    const int h = t >> 5, l = t & 31;
    const float* base = lt + (size_t)b * TWO_N * NHEADS + h;
    float v[32];
    float mx = -1e30f;
    #pragma unroll 8
    for (int i = 0; i < 32; ++i) { v[i] = base[(l + 32 * i) * NHEADS]; mx = fmaxf(mx, v[i]); }
    #pragma unroll
    for (int m = 16; m; m >>= 1) mx = fmaxf(mx, __shfl_xor(mx, m, 32));
    float sm = 0.0f;
    #pragma unroll 8
    for (int i = 0; i < 32; ++i) { v[i] = expf(v[i] - mx); sm += v[i]; }
    #pragma unroll
    for (int m = 16; m; m >>= 1) sm += __shfl_xor(sm, m, 32);
    const float inv = 1.0f / sm;
    #pragma unroll 8
    for (int i = 0; i < 32; ++i) pr[l + 32 * i][h] = v[i] * inv;
  }
  __syncthreads();

  const float* peb = pe + ((size_t)b * TWO_N + ch * 128) * DD;
  float acc[NHEADS] = {0, 0, 0, 0, 0, 0, 0, 0};
  for (int k = 0; k < 128; ++k) {
    const float v = peb[(size_t)k * DD + t];           // coalesced
    const float4 a0 = *(const float4*)&pr[ch * 128 + k][0];   // LDS broadcast
    const float4 a1 = *(const float4*)&pr[ch * 128 + k][4];
    acc[0] += a0.x * v; acc[1] += a0.y * v; acc[2] += a0.z * v; acc[3] += a0.w * v;
    acc[4] += a1.x * v; acc[5] += a1.y * v; acc[6] += a1.z * v; acc[7] += a1.w * v;
  }
  #pragma unroll
  for (int h = 0; h < NHEADS; ++h)
    ctxp[(((size_t)b * 8 + ch) * NHEADS + h) * DD + t] = acc[h];
}

// ---------------------------------------------------------------------------
// Kernel 6: reduce ctx partials + Wv + out_w + W_fc head
// ---------------------------------------------------------------------------
__global__ __launch_bounds__(256) void final_kernel(
    const float* __restrict__ ctxp,
    const float* __restrict__ in_w,  const float* __restrict__ in_b,
    const float* __restrict__ out_w, const float* __restrict__ out_b,
    const float* __restrict__ W_fc,  const float* __restrict__ b_fc,
    float* __restrict__ outp)
{
  __shared__ __align__(16) float ctx_sh[NHEADS * DD];
  __shared__ __align__(16) float o_sh[DD], o2_sh[DD];
  const int t = threadIdx.x;
  const int b = blockIdx.x;

  #pragma unroll
  for (int h = 0; h < NHEADS; ++h) {
    float s = 0.0f;
    #pragma unroll
    for (int ch = 0; ch < 8; ++ch)
      s += ctxp[(((size_t)b * 8 + ch) * NHEADS + h) * DD + t];
    ctx_sh[h * DD + t] = s;
  }
  __syncthreads();
  {
    const float4* wv = (const float4*)(in_w + (size_t)(2 * DD + t) * DD);
    const float4* cx = (const float4*)(ctx_sh + (t >> 5) * DD);
    float o1 = in_b[2 * DD + t];
    #pragma unroll 4
    for (int j = 0; j < DD / 4; ++j) {
      const float4 w4 = wv[j], c4 = cx[j];
      o1 += w4.x * c4.x + w4.y * c4.y + w4.z * c4.z + w4.w * c4.w;
    }
    o_sh[t] = o1;
  }
  __syncthreads();
  {
    const float4* wr = (const float4*)(out_w + (size_t)t * DD);
    const float4* oo = (const float4*)o_sh;
    float o2 = out_b[t];
    #pragma unroll 4
    for (int j = 0; j < DD / 4; ++j) {
      const float4 w4 = wr[j], c4 = oo[j];
      o2 += w4.x * c4.x + w4.y * c4.y + w4.z * c4.z + w4.w * c4.w;
    }
    o2_sh[t] = o2;
  }
  __syncthreads();
  if (t < 6) {
    const float4* wr = (const float4*)(W_fc + (size_t)t * DD);
    const float4* oo = (const float4*)o2_sh;
    float r = b_fc[t];
    for (int j = 0; j < DD / 4; ++j) {
      const float4 w4 = wr[j], c4 = oo[j];
      r += w4.x * c4.x + w4.y * c4.y + w4.z * c4.z + w4.w * c4.w;
    }
    outp[b * 6 + t] = r;
  }
}

// ---------------------------------------------------------------------------
extern "C" void kernel_launch(void* const* d_in, const int* in_sizes, int n_in,
                              void* d_out, int out_size, void* d_ws, size_t ws_size,
                              hipStream_t stream) {
  const float* im0       = (const float*)d_in[0];
  const float* im1       = (const float*)d_in[1];
  const float* kpts0     = (const float*)d_in[2];
  const float* kpts1     = (const float*)d_in[3];
  const float* scores0   = (const float*)d_in[4];
  const float* scores1   = (const float*)d_in[5];
  const float* image_embs= (const float*)d_in[6];
  const int*   smatch    = (const int*)d_in[7];
  const float* ln1_g     = (const float*)d_in[8];
  const float* ln1_b     = (const float*)d_in[9];
  const float* W_pe      = (const float*)d_in[10];
  const float* b_pe      = (const float*)d_in[11];
  const float* ln2_g     = (const float*)d_in[12];
  const float* ln2_b     = (const float*)d_in[13];
  const float* W_proj    = (const float*)d_in[14];
  const float* b_proj    = (const float*)d_in[15];
  const float* in_w      = (const float*)d_in[16];
  const float* in_b      = (const float*)d_in[17];
  const float* out_w     = (const float*)d_in[18];
  const float* out_b     = (const float*)d_in[19];
  const float* W_fc      = (const float*)d_in[20];
  const float* b_fc      = (const float*)d_in[21];

  // ---- workspace layout (bytes) ----
  char* ws = (char*)d_ws;
  size_t off = 0;
  float* epe   = (float*)(ws + off); off += (size_t)ROWS_TOT * DD * 4;        // 32 MB
  float* u     = (float*)(ws + off); off += (size_t)BB * NHEADS * DD * 4;     // 256 KB
  float* ubias = (float*)(ws + off); off += (size_t)BB * NHEADS * 4;
  off = (off + 1023) & ~(size_t)1023;
  float* score = (float*)(ws + off); off += (size_t)ROWS_TOT * 4;             // 128 KB
  float* lt    = (float*)(ws + off); off += (size_t)BB * TWO_N * NHEADS * 4;  // 1 MB
  float* ctxp  = (float*)(ws + off); off += (size_t)BB * 8 * NHEADS * DD * 4; // 2 MB
  unsigned short* Whi = (unsigned short*)(ws + off); off += (size_t)256 * PD_ * 2;
  unsigned short* Wlo = (unsigned short*)(ws + off); off += (size_t)256 * PD_ * 2;
  off = (off + 1023) & ~(size_t)1023;
  unsigned short* Ahi = (unsigned short*)(ws + off); off += (size_t)ROWS_TOT * PD_ * 2; // 50 MB
  unsigned short* Alo = (unsigned short*)(ws + off); off += (size_t)ROWS_TOT * PD_ * 2; // 50 MB

  prep_kernel<<<768 + BB, 256, 0, stream>>>(W_pe, Whi, Wlo,
                                            image_embs, W_proj, b_proj,
                                            in_w, in_b, u, ubias);
  extract_kernel<<<ROWS_TOT / 4, 256, 0, stream>>>(
      im0, im1, kpts0, kpts1, scores0, scores1, smatch,
      ln1_g, ln1_b, Ahi, Alo, score);
  gemm_pe_kernel<<<(ROWS_TOT / 128) * 2, 256, 0, stream>>>(Ahi, Alo, Whi, Wlo, epe);
  ln2_logits_kernel<<<ROWS_TOT / 8, 256, 0, stream>>>(
      epe, b_pe, ln2_g, ln2_b, score, u, ubias, lt);
  ctx_kernel<<<dim3(BB, 8), 256, 0, stream>>>(epe, lt, ctxp);
  final_kernel<<<BB, 256, 0, stream>>>(ctxp, in_w, in_b, out_w, out_b,
                                       W_fc, b_fc, (float*)d_out);
}